// Round 23
// baseline (402.993 us; speedup 1.0000x reference)
//
#include <hip/hip_runtime.h>

#define T_SEQ  2048
#define HID    4096
#define NQH    32
#define NKVH   8
#define HDIM   128

typedef float  f32x4  __attribute__((ext_vector_type(4)));
typedef __bf16 bf16x8 __attribute__((ext_vector_type(8)));

__device__ __forceinline__ float bf2f(unsigned short u) {
  union { unsigned int i; float f; } v; v.i = ((unsigned int)u) << 16; return v.f;
}
__device__ __forceinline__ unsigned short f2bf(float f) {
  union { float f; unsigned int i; } v; v.f = f;
  unsigned int r = v.i + 0x7fffu + ((v.i >> 16) & 1u);
  return (unsigned short)(r >> 16);
}

__device__ __forceinline__ f32x4 mfma_bf16(bf16x8 a, bf16x8 b, f32x4 c) {
  return __builtin_amdgcn_mfma_f32_16x16x32_bf16(a, b, c, 0, 0, 0);
}

#define GLOAD16(g, l)                                              \
  __builtin_amdgcn_global_load_lds(                                \
      (const __attribute__((address_space(1))) void*)(g),          \
      (__attribute__((address_space(3))) void*)(l), 16, 0, 0)

// ---------------------------------------------------------------- prep: hs convert + wq/wk/wv transposes
__global__ void prep_all(const float* __restrict__ hs, unsigned short* __restrict__ hb,
                         const float* __restrict__ wq, unsigned short* __restrict__ wqt,
                         const float* __restrict__ wk, const float* __restrict__ wv,
                         unsigned short* __restrict__ wkvt) {
  __shared__ float tile[64][65];
  const int b = blockIdx.x;
  if (b < 8192) {
    long long i = ((long long)b * 256 + threadIdx.x) * 4;
    float4 v = *(const float4*)(hs + i);
    union { unsigned short u[4]; uint2 p; } o;
    o.u[0] = f2bf(v.x); o.u[1] = f2bf(v.y); o.u[2] = f2bf(v.z); o.u[3] = f2bf(v.w);
    *(uint2*)(hb + i) = o.p;
    return;
  }
  const float* W;
  unsigned short* dst;
  int N, n0, k0;
  if (b < 12288) {
    int bid = b - 8192;  W = wq;  dst = wqt;  N = 4096;
    n0 = (bid & 63) * 64; k0 = (bid >> 6) * 64;
  } else if (b < 13312) {
    int bid = b - 12288; W = wk;  dst = wkvt; N = 1024;
    n0 = (bid & 15) * 64; k0 = (bid >> 4) * 64;
  } else {
    int bid = b - 13312; W = wv;  dst = wkvt + (size_t)1024 * HID; N = 1024;
    n0 = (bid & 15) * 64; k0 = (bid >> 4) * 64;
  }
  int tx = threadIdx.x & 15, ty = threadIdx.x >> 4;
#pragma unroll
  for (int i = 0; i < 4; i++) {
    int k = ty + 16 * i;
    float4 f = *(const float4*)(W + (long long)(k0 + k) * N + n0 + tx * 4);
    tile[tx * 4 + 0][k] = f.x;
    tile[tx * 4 + 1][k] = f.y;
    tile[tx * 4 + 2][k] = f.z;
    tile[tx * 4 + 3][k] = f.w;
  }
  __syncthreads();
#pragma unroll
  for (int i = 0; i < 4; i++) {
    int n = ty + 16 * i;
    union { unsigned short u[4]; uint2 p; } o;
    o.u[0] = f2bf(tile[n][tx * 4 + 0]);
    o.u[1] = f2bf(tile[n][tx * 4 + 1]);
    o.u[2] = f2bf(tile[n][tx * 4 + 2]);
    o.u[3] = f2bf(tile[n][tx * 4 + 3]);
    *(uint2*)(dst + (long long)(n0 + n) * HID + k0 + tx * 4) = o.p;
  }
}

// ---------------------------------------------------------------- transpose 64x64 tile (wo)
__global__ void transpose_conv(const float* __restrict__ W,
                               unsigned short* __restrict__ Wt, int K, int N) {
  __shared__ float tile[64][65];
  int n0 = blockIdx.x * 64, k0 = blockIdx.y * 64;
  int tx = threadIdx.x & 15, ty = threadIdx.x >> 4;
#pragma unroll
  for (int i = 0; i < 4; i++) {
    int k = ty + 16 * i;
    float4 f = *(const float4*)(W + (long long)(k0 + k) * N + n0 + tx * 4);
    tile[tx * 4 + 0][k] = f.x;
    tile[tx * 4 + 1][k] = f.y;
    tile[tx * 4 + 2][k] = f.z;
    tile[tx * 4 + 3][k] = f.w;
  }
  __syncthreads();
#pragma unroll
  for (int i = 0; i < 4; i++) {
    int n = ty + 16 * i;
    union { unsigned short u[4]; uint2 p; } o;
    o.u[0] = f2bf(tile[n][tx * 4 + 0]);
    o.u[1] = f2bf(tile[n][tx * 4 + 1]);
    o.u[2] = f2bf(tile[n][tx * 4 + 2]);
    o.u[3] = f2bf(tile[n][tx * 4 + 3]);
    *(uint2*)(Wt + (long long)(n0 + n) * K + k0 + tx * 4) = o.p;
  }
}

// ---------------------------------------------------------------- split-K GEMM: M=2048, N=4096, K=4096, KSPLIT=2
// grid (32,16,2): z selects K-half and partial buffer (bf16). Tile/swizzle mapping per z
// identical to the verified r17 Q-GEMM (512 blocks, 512%8==0 -> same XCD per (bx,by) pair).
__global__ __launch_bounds__(256) void gemm_sk(const unsigned short* __restrict__ A,
                                               const unsigned short* __restrict__ Bt,
                                               unsigned short* __restrict__ P0,
                                               unsigned short* __restrict__ P1) {
  __shared__ unsigned short As[128 * 64];
  __shared__ unsigned short Bs[128 * 64];
  const int K = HID;
  const int kbeg = blockIdx.z * (HID / 2), kend = kbeg + (HID / 2);
  unsigned short* P = blockIdx.z ? P1 : P0;

  const int lin = blockIdx.y * gridDim.x + blockIdx.x;  // 0..511
  const int cpx = (gridDim.x * gridDim.y) >> 3;         // 64
  const int swz = (lin & 7) * cpx + (lin >> 3);
  const int bx = swz % gridDim.x, by = swz / gridDim.x;

  const int t = threadIdx.x;
  const int lane = t & 63, w = t >> 6;
  const int wr = w >> 1, wc = w & 1;
  const int l15 = lane & 15, lg = lane >> 4;
  const int m0 = by * 128, n0 = bx * 128;

  f32x4 acc[4][4];
#pragma unroll
  for (int i = 0; i < 4; i++)
#pragma unroll
    for (int j = 0; j < 4; j++) acc[i][j] = (f32x4){0.f, 0.f, 0.f, 0.f};

  for (int kt = kbeg; kt < kend; kt += 64) {
    __syncthreads();
#pragma unroll
    for (int s = 0; s < 4; s++) {
      int c = t + s * 256;
      int row = c >> 3, sub = c & 7;
      GLOAD16(A + (long long)(m0 + row) * K + kt + ((sub ^ (row & 7)) * 8),
              (char*)As + (w * 64 + s * 256) * 16);
      GLOAD16(Bt + (long long)(n0 + row) * K + kt + ((sub ^ (row & 7)) * 8),
              (char*)Bs + (w * 64 + s * 256) * 16);
    }
    __syncthreads();

#pragma unroll
    for (int kk = 0; kk < 2; kk++) {
      bf16x8 af[4], bfr[4];
#pragma unroll
      for (int mi = 0; mi < 4; mi++) {
        int row = wr * 64 + mi * 16 + l15;
        af[mi] = *(const bf16x8*)(As + row * 64 + (((kk * 4 + lg) ^ (row & 7)) * 8));
      }
#pragma unroll
      for (int ni = 0; ni < 4; ni++) {
        int row = wc * 64 + ni * 16 + l15;
        bfr[ni] = *(const bf16x8*)(Bs + row * 64 + (((kk * 4 + lg) ^ (row & 7)) * 8));
      }
#pragma unroll
      for (int mi = 0; mi < 4; mi++)
#pragma unroll
        for (int ni = 0; ni < 4; ni++)
          acc[mi][ni] = mfma_bf16(af[mi], bfr[ni], acc[mi][ni]);
    }
  }

  const int row0 = m0 + wr * 64, col0 = n0 + wc * 64;
#pragma unroll
  for (int mi = 0; mi < 4; mi++)
#pragma unroll
    for (int ni = 0; ni < 4; ni++) {
      int rbase = row0 + mi * 16 + lg * 4;
      int col = col0 + ni * 16 + l15;
#pragma unroll
      for (int r = 0; r < 4; r++)
        P[(long long)(rbase + r) * 4096 + col] = f2bf(acc[mi][ni][r]);
    }
}

// ---------------------------------------------------------------- KV GEMM v3: BM=64, BK=64 + XOR swizzle (r17-proven)
__global__ __launch_bounds__(256) void gemm_kv64(const unsigned short* __restrict__ A,
                                                 const unsigned short* __restrict__ Bt,
                                                 unsigned short* __restrict__ Ckv,
                                                 unsigned short* __restrict__ Cvt) {
  __shared__ unsigned short As[64 * 64];
  __shared__ unsigned short Bs[128 * 64];
  __shared__ unsigned short Tt[128 * 64];
  const int lin = blockIdx.y * gridDim.x + blockIdx.x;  // grid (16,32) = 512
  const int swz = (lin & 7) * 64 + (lin >> 3);
  const int bx = swz & 15, by = swz >> 4;

  const int t = threadIdx.x;
  const int lane = t & 63, w = t >> 6;
  const int wr = w >> 1, wc = w & 1;
  const int l15 = lane & 15, lg = lane >> 4;
  const int m0 = by * 64, n0 = bx * 128;
  const int K = HID;

  f32x4 acc[2][4];
#pragma unroll
  for (int i = 0; i < 2; i++)
#pragma unroll
    for (int j = 0; j < 4; j++) acc[i][j] = (f32x4){0.f, 0.f, 0.f, 0.f};

  for (int kt = 0; kt < K; kt += 64) {
    __syncthreads();
#pragma unroll
    for (int s = 0; s < 2; s++) {
      int c = t + s * 256;
      int row = c >> 3, sub = c & 7;
      GLOAD16(A + (long long)(m0 + row) * K + kt + ((sub ^ (row & 7)) * 8),
              (char*)As + (w * 64 + s * 256) * 16);
    }
#pragma unroll
    for (int s = 0; s < 4; s++) {
      int c = t + s * 256;
      int row = c >> 3, sub = c & 7;
      GLOAD16(Bt + (long long)(n0 + row) * K + kt + ((sub ^ (row & 7)) * 8),
              (char*)Bs + (w * 64 + s * 256) * 16);
    }
    __syncthreads();

#pragma unroll
    for (int kk = 0; kk < 2; kk++) {
      bf16x8 af[2], bfr[4];
#pragma unroll
      for (int mi = 0; mi < 2; mi++) {
        int row = wr * 32 + mi * 16 + l15;
        af[mi] = *(const bf16x8*)(As + row * 64 + (((kk * 4 + lg) ^ (row & 7)) * 8));
      }
#pragma unroll
      for (int ni = 0; ni < 4; ni++) {
        int row = wc * 64 + ni * 16 + l15;
        bfr[ni] = *(const bf16x8*)(Bs + row * 64 + (((kk * 4 + lg) ^ (row & 7)) * 8));
      }
#pragma unroll
      for (int mi = 0; mi < 2; mi++)
#pragma unroll
        for (int ni = 0; ni < 4; ni++)
          acc[mi][ni] = mfma_bf16(af[mi], bfr[ni], acc[mi][ni]);
    }
  }

  const int row0 = m0 + wr * 32, col0 = n0 + wc * 64;
  if (n0 < 1024) {
#pragma unroll
    for (int mi = 0; mi < 2; mi++)
#pragma unroll
      for (int ni = 0; ni < 4; ni++) {
        int rbase = row0 + mi * 16 + lg * 4;
        int col = col0 + ni * 16 + l15;
#pragma unroll
        for (int r = 0; r < 4; r++)
          Ckv[(long long)(rbase + r) * 1024 + col] = f2bf(acc[mi][ni][r]);
      }
  } else {
#pragma unroll
    for (int mi = 0; mi < 2; mi++)
#pragma unroll
      for (int ni = 0; ni < 4; ni++) {
        int nloc = wc * 64 + ni * 16 + l15;
#pragma unroll
        for (int r = 0; r < 4; r++) {
          int mloc = wr * 32 + mi * 16 + lg * 4 + r;
          Tt[nloc * 64 + (mloc ^ ((nloc & 7) << 3))] = f2bf(acc[mi][ni][r]);
        }
      }
    __syncthreads();
    const int nloc = t >> 1;
#pragma unroll
    for (int cc = 0; cc < 8; cc++) {
      int ci = (t & 1) * 8 + cc;
      uint2 v = *(const uint2*)(Tt + nloc * 64 +
                                (((ci >> 1) ^ (nloc & 7)) * 8 + (ci & 1) * 4));
      int nc = (ci >> 3) * 8 + 2 * (ci & 3) + ((ci >> 2) & 1);
      *(uint2*)(Cvt + (long long)(n0 - 1024 + nloc) * T_SEQ + m0 + nc * 4) = v;
    }
  }
}

// ---------------------------------------------------------------- RoPE + Q split-K reduce; zeroes queue counters
// Q rows: x = partial0(qb) + partial1(qp1), then rope (scale folded), write qb.
__global__ void rope_all(unsigned short* __restrict__ qb,
                         const unsigned short* __restrict__ qp1,
                         unsigned short* __restrict__ kb,
                         const int* __restrict__ positions,
                         int* __restrict__ cnt) {
  if (blockIdx.x == 0 && threadIdx.x < 8) cnt[threadIdx.x] = 0;
  const int w = threadIdx.x >> 6, d = threadIdx.x & 63;
  const int gid = blockIdx.x * 4 + w;
  int t;
  double inv = exp2(-(double)d * 0.20762050593046014);
  if (gid < T_SEQ * NQH) {
    int h = gid & (NQH - 1); t = gid >> 5;
    size_t off = (size_t)t * (NQH * HDIM) + (size_t)h * HDIM;
    unsigned short* row = qb + off;
    const unsigned short* row1 = qp1 + off;
    double ang = (double)positions[t] * inv;
    double c = cos(ang) * 0.12751744416986895, s = sin(ang) * 0.12751744416986895;
    float x1 = bf2f(row[d]) + bf2f(row1[d]);
    float x2 = bf2f(row[d + 64]) + bf2f(row1[d + 64]);
    row[d]      = f2bf((float)((double)x1 * c - (double)x2 * s));
    row[d + 64] = f2bf((float)((double)x2 * c + (double)x1 * s));
  } else {
    int g = gid - T_SEQ * NQH;
    int h = g & (NKVH - 1); t = g >> 3;
    unsigned short* row = kb + (size_t)t * (NKVH * HDIM) + (size_t)h * HDIM;
    double ang = (double)positions[t] * inv;
    double c = cos(ang), s = sin(ang);
    float x1 = bf2f(row[d]), x2 = bf2f(row[d + 64]);
    row[d]      = f2bf((float)((double)x1 * c - (double)x2 * s));
    row[d + 64] = f2bf((float)((double)x2 * c + (double)x1 * s));
  }
}

// ---------------------------------------------------------------- O split-K reduce: out = f32(p0) + f32(p1)
__global__ void reduce_o(const unsigned short* __restrict__ p0,
                         const unsigned short* __restrict__ p1,
                         float* __restrict__ out) {
  long long i = ((long long)blockIdx.x * 256 + threadIdx.x) * 4;
  uint2 a = *(const uint2*)(p0 + i);
  uint2 b = *(const uint2*)(p1 + i);
  float4 o;
  o.x = bf2f((unsigned short)(a.x & 0xffff)) + bf2f((unsigned short)(b.x & 0xffff));
  o.y = bf2f((unsigned short)(a.x >> 16))    + bf2f((unsigned short)(b.x >> 16));
  o.z = bf2f((unsigned short)(a.y & 0xffff)) + bf2f((unsigned short)(b.y & 0xffff));
  o.w = bf2f((unsigned short)(a.y >> 16))    + bf2f((unsigned short)(b.y >> 16));
  *(float4*)(out + i) = o;
}

// ---------------------------------------------------------------- flash attention v15: persistent queue + dbuf staging (r22)
__global__ __launch_bounds__(256) void attn_kernel(const unsigned short* __restrict__ qb,
                                                   const unsigned short* __restrict__ kb,
                                                   const unsigned short* __restrict__ vt,
                                                   unsigned short* __restrict__ ab,
                                                   int* __restrict__ cnt) {
  __shared__ unsigned short Ks[2][64 * 128];
  __shared__ unsigned short Vs[2][128 * 64];
  __shared__ int s_item;

  const int xcd = blockIdx.x & 7;
  const int kvh = xcd;
  const int t = threadIdx.x, lane = t & 63, w = t >> 6;
  const int l15 = lane & 15, lg = lane >> 4;

  auto stage = [&](int kts, int bsel) {
#pragma unroll
    for (int s = 0; s < 4; s++) {
      int c = t + s * 256;
      int row = c >> 4, chk = c & 15;
      GLOAD16(kb + (long long)(kts * 64 + row) * (NKVH * HDIM) + kvh * HDIM +
                  ((chk ^ (row & 7)) * 8),
              (char*)(&Ks[bsel][0]) + (w * 64 + s * 256) * 16);
    }
#pragma unroll
    for (int s = 0; s < 4; s++) {
      int c = t + s * 256;
      int row = c >> 3, chk = c & 7;
      GLOAD16(vt + (long long)(kvh * HDIM + row) * T_SEQ + kts * 64 +
                  ((chk ^ (row & 7)) * 8),
              (char*)(&Vs[bsel][0]) + (w * 64 + s * 256) * 16);
    }
  };

  for (;;) {
    __syncthreads();
    if (t == 0) s_item = atomicAdd(&cnt[xcd], 1);
    __syncthreads();
    const int item = s_item;
    if (item >= 128) break;
    const int j = 31 - (item >> 2);
    const int head = xcd * 4 + (item & 3);
    const int q0 = j * 64;

    bf16x8 qf[4];
#pragma unroll
    for (int kk = 0; kk < 4; kk++)
      qf[kk] = *(const bf16x8*)(qb + (long long)(q0 + w * 16 + l15) * (NQH * HDIM) +
                                head * HDIM + kk * 32 + lg * 8);

    f32x4 accO[8];
#pragma unroll
    for (int db = 0; db < 8; db++) accO[db] = (f32x4){0.f, 0.f, 0.f, 0.f};
    float mrun = -3e38f, lrun = 0.f;

    stage(0, 0);
    for (int kt = 0; kt <= j; kt++) {
      const int cur = kt & 1;
      __syncthreads();
      if (kt < j) stage(kt + 1, cur ^ 1);

      f32x4 accS[4];
#pragma unroll
      for (int kc = 0; kc < 4; kc++) accS[kc] = (f32x4){0.f, 0.f, 0.f, 0.f};
      __builtin_amdgcn_s_setprio(1);
#pragma unroll
      for (int kk = 0; kk < 4; kk++)
#pragma unroll
        for (int kc = 0; kc < 4; kc++) {
          int row = kc * 16 + l15;
          bf16x8 a = *(const bf16x8*)(&Ks[cur][0] + row * 128 + (((kk * 4 + lg) ^ (l15 & 7)) * 8));
          accS[kc] = mfma_bf16(a, qf[kk], accS[kc]);
        }
      __builtin_amdgcn_s_setprio(0);

      float pm[4][4];
      if (kt == j) {
        const int qloc = w * 16 + l15;
#pragma unroll
        for (int kc = 0; kc < 4; kc++)
#pragma unroll
          for (int r = 0; r < 4; r++)
            pm[kc][r] = (kc * 16 + lg * 4 + r > qloc) ? -3e38f : accS[kc][r];
      } else {
#pragma unroll
        for (int kc = 0; kc < 4; kc++)
#pragma unroll
          for (int r = 0; r < 4; r++) pm[kc][r] = accS[kc][r];
      }

      float rm = pm[0][0];
#pragma unroll
      for (int kc = 0; kc < 4; kc++)
#pragma unroll
        for (int r = 0; r < 4; r++) rm = fmaxf(rm, pm[kc][r]);
      if (__any(rm > mrun + 8.f)) {
        rm = fmaxf(rm, __shfl_xor(rm, 16, 64));
        rm = fmaxf(rm, __shfl_xor(rm, 32, 64));
        float mn = fmaxf(mrun, rm);
        float corr = exp2f(mrun - mn);
        mrun = mn;
        lrun *= corr;
        float cO[4];
#pragma unroll
        for (int r = 0; r < 4; r++) cO[r] = __shfl(corr, lg * 4 + r, 64);
#pragma unroll
        for (int db = 0; db < 8; db++)
#pragma unroll
          for (int r = 0; r < 4; r++) accO[db][r] *= cO[r];
      }

      float p[4][4];
#pragma unroll
      for (int kc = 0; kc < 4; kc++)
#pragma unroll
        for (int r = 0; r < 4; r++) {
          p[kc][r] = exp2f(pm[kc][r] - mrun);
          lrun += p[kc][r];
        }
      bf16x8 pa0, pa1;
#pragma unroll
      for (int jj = 0; jj < 8; jj++) {
        pa0[jj] = (__bf16)p[(jj >> 2)][jj & 3];
        pa1[jj] = (__bf16)p[2 + (jj >> 2)][jj & 3];
      }

      __builtin_amdgcn_s_setprio(1);
#pragma unroll
      for (int db = 0; db < 8; db++) {
        int vrow = db * 16 + l15;
        bf16x8 b = *(const bf16x8*)(&Vs[cur][0] + vrow * 64 + ((lg ^ (vrow & 7)) * 8));
        accO[db] = mfma_bf16(pa0, b, accO[db]);
      }
#pragma unroll
      for (int db = 0; db < 8; db++) {
        int vrow = db * 16 + l15;
        bf16x8 b = *(const bf16x8*)(&Vs[cur][0] + vrow * 64 + (((4 + lg) ^ (vrow & 7)) * 8));
        accO[db] = mfma_bf16(pa1, b, accO[db]);
      }
      __builtin_amdgcn_s_setprio(0);
    }

    lrun += __shfl_xor(lrun, 16, 64);
    lrun += __shfl_xor(lrun, 32, 64);
    float lO[4];
#pragma unroll
    for (int r = 0; r < 4; r++) lO[r] = __shfl(lrun, lg * 4 + r, 64);
#pragma unroll
    for (int db = 0; db < 8; db++)
#pragma unroll
      for (int r = 0; r < 4; r++) {
        int qr = q0 + w * 16 + lg * 4 + r;
        int col = head * HDIM + db * 16 + l15;
        ((__bf16*)ab)[(long long)qr * (NQH * HDIM) + col] = (__bf16)(accO[db][r] / lO[r]);
      }
  }
}

// ---------------------------------------------------------------- launch
extern "C" void kernel_launch(void* const* d_in, const int* in_sizes, int n_in,
                              void* d_out, int out_size, void* d_ws, size_t ws_size,
                              hipStream_t stream) {
  const int*   positions = (const int*)d_in[0];
  const float* hs = (const float*)d_in[1];
  const float* wq = (const float*)d_in[2];
  const float* wk = (const float*)d_in[3];
  const float* wv = (const float*)d_in[4];
  const float* wo = (const float*)d_in[5];
  float* out = (float*)d_out;

  // workspace: wqt 33.6 + wkvt 16.8 + hb/ab 16.8 + qb 16.8 + kb 4.2 + vtb 4.2 + cnt = 92.3 MB (proven)
  const size_t SZ_WQT = (size_t)HID * HID * 2;
  const size_t SZ_WKV = (size_t)2048 * HID * 2;
  const size_t SZ_HB  = (size_t)T_SEQ * HID * 2;
  const size_t SZ_QB  = (size_t)T_SEQ * NQH * HDIM * 2;
  const size_t SZ_KB  = (size_t)T_SEQ * NKVH * HDIM * 2;
  const size_t need = SZ_WQT + SZ_WKV + SZ_HB + SZ_QB + SZ_KB * 2 + 64;
  if (ws_size < need) return;  // absmax 4.625 signature

  char* p = (char*)d_ws;
  unsigned short* wqt  = (unsigned short*)p; p += SZ_WQT;  // reused for wo_t at the end
  unsigned short* wkvt = (unsigned short*)p; p += SZ_WKV;  // reused as O-partial p1
  unsigned short* hb   = (unsigned short*)p; p += SZ_HB;
  unsigned short* qb   = (unsigned short*)p; p += SZ_QB;   // Q-partial p0, then q; later O-partial p0
  unsigned short* kb   = (unsigned short*)p; p += SZ_KB;
  unsigned short* vtb  = (unsigned short*)p; p += SZ_KB;
  int* cnt = (int*)p;
  unsigned short* ab   = hb;                // alias: hb dead after KV-GEMM
  unsigned short* qp1  = (unsigned short*)out;  // out as scratch for Q-partial p1

  prep_all<<<14336, 256, 0, stream>>>(hs, hb, wq, wqt, wk, wv, wkvt);

  // Q projection, split-K=2: partials -> qb (z=0) and out-as-bf16 (z=1)
  gemm_sk<<<dim3(32, 16, 2), 256, 0, stream>>>(hb, wqt, qb, qp1);
  gemm_kv64<<<dim3(16, 32), 256, 0, stream>>>(hb, wkvt, kb, vtb);

  // rope fuses the Q-partial reduce; zeroes attn queue counters
  rope_all<<<(T_SEQ * (NQH + NKVH)) / 4, 256, 0, stream>>>(qb, qp1, kb, positions, cnt);

  attn_kernel<<<512, 256, 0, stream>>>(qb, kb, vtb, ab, cnt);

  // O projection, split-K=2: partials -> qb (z=0, dead) and wkvt (z=1, dead); then reduce
  transpose_conv<<<dim3(HID / 64, (NQH * HDIM) / 64), 256, 0, stream>>>(wo, wqt, NQH * HDIM, HID);
  gemm_sk<<<dim3(32, 16, 2), 256, 0, stream>>>(ab, wqt, qb, wkvt);
  reduce_o<<<(T_SEQ * HID) / 1024, 256, 0, stream>>>(qb, wkvt, out);
}

// Round 24
// 356.400 us; speedup vs baseline: 1.1307x; 1.1307x over previous
//
#include <hip/hip_runtime.h>

#define T_SEQ  2048
#define HID    4096
#define NQH    32
#define NKVH   8
#define HDIM   128

typedef float  f32x4  __attribute__((ext_vector_type(4)));
typedef __bf16 bf16x8 __attribute__((ext_vector_type(8)));

__device__ __forceinline__ float bf2f(unsigned short u) {
  union { unsigned int i; float f; } v; v.i = ((unsigned int)u) << 16; return v.f;
}
__device__ __forceinline__ unsigned short f2bf(float f) {
  union { float f; unsigned int i; } v; v.f = f;
  unsigned int r = v.i + 0x7fffu + ((v.i >> 16) & 1u);
  return (unsigned short)(r >> 16);
}

__device__ __forceinline__ f32x4 mfma_bf16(bf16x8 a, bf16x8 b, f32x4 c) {
  return __builtin_amdgcn_mfma_f32_16x16x32_bf16(a, b, c, 0, 0, 0);
}

#define GLOAD16(g, l)                                              \
  __builtin_amdgcn_global_load_lds(                                \
      (const __attribute__((address_space(1))) void*)(g),          \
      (__attribute__((address_space(3))) void*)(l), 16, 0, 0)

// ---------------------------------------------------------------- prep: hs convert + wq/wk/wv transposes (one launch)
__global__ void prep_all(const float* __restrict__ hs, unsigned short* __restrict__ hb,
                         const float* __restrict__ wq, unsigned short* __restrict__ wqt,
                         const float* __restrict__ wk, const float* __restrict__ wv,
                         unsigned short* __restrict__ wkvt) {
  __shared__ float tile[64][65];
  const int b = blockIdx.x;
  if (b < 8192) {
    long long i = ((long long)b * 256 + threadIdx.x) * 4;
    float4 v = *(const float4*)(hs + i);
    union { unsigned short u[4]; uint2 p; } o;
    o.u[0] = f2bf(v.x); o.u[1] = f2bf(v.y); o.u[2] = f2bf(v.z); o.u[3] = f2bf(v.w);
    *(uint2*)(hb + i) = o.p;
    return;
  }
  const float* W;
  unsigned short* dst;
  int N, n0, k0;
  if (b < 12288) {
    int bid = b - 8192;  W = wq;  dst = wqt;  N = 4096;
    n0 = (bid & 63) * 64; k0 = (bid >> 6) * 64;
  } else if (b < 13312) {
    int bid = b - 12288; W = wk;  dst = wkvt; N = 1024;
    n0 = (bid & 15) * 64; k0 = (bid >> 4) * 64;
  } else {
    int bid = b - 13312; W = wv;  dst = wkvt + (size_t)1024 * HID; N = 1024;
    n0 = (bid & 15) * 64; k0 = (bid >> 4) * 64;
  }
  int tx = threadIdx.x & 15, ty = threadIdx.x >> 4;
#pragma unroll
  for (int i = 0; i < 4; i++) {
    int k = ty + 16 * i;
    float4 f = *(const float4*)(W + (long long)(k0 + k) * N + n0 + tx * 4);
    tile[tx * 4 + 0][k] = f.x;
    tile[tx * 4 + 1][k] = f.y;
    tile[tx * 4 + 2][k] = f.z;
    tile[tx * 4 + 3][k] = f.w;
  }
  __syncthreads();
#pragma unroll
  for (int i = 0; i < 4; i++) {
    int n = ty + 16 * i;
    union { unsigned short u[4]; uint2 p; } o;
    o.u[0] = f2bf(tile[n][tx * 4 + 0]);
    o.u[1] = f2bf(tile[n][tx * 4 + 1]);
    o.u[2] = f2bf(tile[n][tx * 4 + 2]);
    o.u[3] = f2bf(tile[n][tx * 4 + 3]);
    *(uint2*)(dst + (long long)(n0 + n) * HID + k0 + tx * 4) = o.p;
  }
}

// ---------------------------------------------------------------- transpose 64x64 tile (wo)
__global__ void transpose_conv(const float* __restrict__ W,
                               unsigned short* __restrict__ Wt, int K, int N) {
  __shared__ float tile[64][65];
  int n0 = blockIdx.x * 64, k0 = blockIdx.y * 64;
  int tx = threadIdx.x & 15, ty = threadIdx.x >> 4;
#pragma unroll
  for (int i = 0; i < 4; i++) {
    int k = ty + 16 * i;
    float4 f = *(const float4*)(W + (long long)(k0 + k) * N + n0 + tx * 4);
    tile[tx * 4 + 0][k] = f.x;
    tile[tx * 4 + 1][k] = f.y;
    tile[tx * 4 + 2][k] = f.z;
    tile[tx * 4 + 3][k] = f.w;
  }
  __syncthreads();
#pragma unroll
  for (int i = 0; i < 4; i++) {
    int n = ty + 16 * i;
    union { unsigned short u[4]; uint2 p; } o;
    o.u[0] = f2bf(tile[n][tx * 4 + 0]);
    o.u[1] = f2bf(tile[n][tx * 4 + 1]);
    o.u[2] = f2bf(tile[n][tx * 4 + 2]);
    o.u[3] = f2bf(tile[n][tx * 4 + 3]);
    *(uint2*)(Wt + (long long)(n0 + n) * K + k0 + tx * 4) = o.p;
  }
}

// ---------------------------------------------------------------- GEMM: BM=128, BK=64 + XOR swizzle + XCD swizzle
template <int EPI>
__global__ __launch_bounds__(256) void gemm_bt(const unsigned short* __restrict__ A,
                                               const unsigned short* __restrict__ Bt,
                                               void* __restrict__ Cv,
                                               int M, int N, int K) {
  __shared__ unsigned short As[128 * 64];
  __shared__ unsigned short Bs[128 * 64];
  const int lin = blockIdx.y * gridDim.x + blockIdx.x;
  const int cpx = (gridDim.x * gridDim.y) >> 3;
  const int swz = (lin & 7) * cpx + (lin >> 3);
  const int bx = swz % gridDim.x, by = swz / gridDim.x;

  const int t = threadIdx.x;
  const int lane = t & 63, w = t >> 6;
  const int wr = w >> 1, wc = w & 1;
  const int l15 = lane & 15, lg = lane >> 4;
  const int m0 = by * 128, n0 = bx * 128;

  f32x4 acc[4][4];
#pragma unroll
  for (int i = 0; i < 4; i++)
#pragma unroll
    for (int j = 0; j < 4; j++) acc[i][j] = (f32x4){0.f, 0.f, 0.f, 0.f};

  for (int kt = 0; kt < K; kt += 64) {
    __syncthreads();
#pragma unroll
    for (int s = 0; s < 4; s++) {
      int c = t + s * 256;
      int row = c >> 3, sub = c & 7;
      GLOAD16(A + (long long)(m0 + row) * K + kt + ((sub ^ (row & 7)) * 8),
              (char*)As + (w * 64 + s * 256) * 16);
      GLOAD16(Bt + (long long)(n0 + row) * K + kt + ((sub ^ (row & 7)) * 8),
              (char*)Bs + (w * 64 + s * 256) * 16);
    }
    __syncthreads();

#pragma unroll
    for (int kk = 0; kk < 2; kk++) {
      bf16x8 af[4], bfr[4];
#pragma unroll
      for (int mi = 0; mi < 4; mi++) {
        int row = wr * 64 + mi * 16 + l15;
        af[mi] = *(const bf16x8*)(As + row * 64 + (((kk * 4 + lg) ^ (row & 7)) * 8));
      }
#pragma unroll
      for (int ni = 0; ni < 4; ni++) {
        int row = wc * 64 + ni * 16 + l15;
        bfr[ni] = *(const bf16x8*)(Bs + row * 64 + (((kk * 4 + lg) ^ (row & 7)) * 8));
      }
#pragma unroll
      for (int mi = 0; mi < 4; mi++)
#pragma unroll
        for (int ni = 0; ni < 4; ni++)
          acc[mi][ni] = mfma_bf16(af[mi], bfr[ni], acc[mi][ni]);
    }
  }

  const int row0 = m0 + wr * 64, col0 = n0 + wc * 64;
#pragma unroll
  for (int mi = 0; mi < 4; mi++)
#pragma unroll
    for (int ni = 0; ni < 4; ni++) {
      int rbase = row0 + mi * 16 + lg * 4;
      int col = col0 + ni * 16 + l15;
#pragma unroll
      for (int r = 0; r < 4; r++) {
        float v = acc[mi][ni][r];
        if (EPI == 0)
          ((unsigned short*)Cv)[(long long)(rbase + r) * N + col] = f2bf(v);
        else
          ((float*)Cv)[(long long)(rbase + r) * N + col] = v;
      }
    }
}

// ---------------------------------------------------------------- KV GEMM v3: BM=64, BK=64 + XOR swizzle
__global__ __launch_bounds__(256) void gemm_kv64(const unsigned short* __restrict__ A,
                                                 const unsigned short* __restrict__ Bt,
                                                 unsigned short* __restrict__ Ckv,
                                                 unsigned short* __restrict__ Cvt) {
  __shared__ unsigned short As[64 * 64];
  __shared__ unsigned short Bs[128 * 64];
  __shared__ unsigned short Tt[128 * 64];
  const int lin = blockIdx.y * gridDim.x + blockIdx.x;  // grid (16,32) = 512
  const int swz = (lin & 7) * 64 + (lin >> 3);
  const int bx = swz & 15, by = swz >> 4;

  const int t = threadIdx.x;
  const int lane = t & 63, w = t >> 6;
  const int wr = w >> 1, wc = w & 1;
  const int l15 = lane & 15, lg = lane >> 4;
  const int m0 = by * 64, n0 = bx * 128;
  const int K = HID;

  f32x4 acc[2][4];
#pragma unroll
  for (int i = 0; i < 2; i++)
#pragma unroll
    for (int j = 0; j < 4; j++) acc[i][j] = (f32x4){0.f, 0.f, 0.f, 0.f};

  for (int kt = 0; kt < K; kt += 64) {
    __syncthreads();
#pragma unroll
    for (int s = 0; s < 2; s++) {
      int c = t + s * 256;
      int row = c >> 3, sub = c & 7;
      GLOAD16(A + (long long)(m0 + row) * K + kt + ((sub ^ (row & 7)) * 8),
              (char*)As + (w * 64 + s * 256) * 16);
    }
#pragma unroll
    for (int s = 0; s < 4; s++) {
      int c = t + s * 256;
      int row = c >> 3, sub = c & 7;
      GLOAD16(Bt + (long long)(n0 + row) * K + kt + ((sub ^ (row & 7)) * 8),
              (char*)Bs + (w * 64 + s * 256) * 16);
    }
    __syncthreads();

#pragma unroll
    for (int kk = 0; kk < 2; kk++) {
      bf16x8 af[2], bfr[4];
#pragma unroll
      for (int mi = 0; mi < 2; mi++) {
        int row = wr * 32 + mi * 16 + l15;
        af[mi] = *(const bf16x8*)(As + row * 64 + (((kk * 4 + lg) ^ (row & 7)) * 8));
      }
#pragma unroll
      for (int ni = 0; ni < 4; ni++) {
        int row = wc * 64 + ni * 16 + l15;
        bfr[ni] = *(const bf16x8*)(Bs + row * 64 + (((kk * 4 + lg) ^ (row & 7)) * 8));
      }
#pragma unroll
      for (int mi = 0; mi < 2; mi++)
#pragma unroll
        for (int ni = 0; ni < 4; ni++)
          acc[mi][ni] = mfma_bf16(af[mi], bfr[ni], acc[mi][ni]);
    }
  }

  const int row0 = m0 + wr * 32, col0 = n0 + wc * 64;
  if (n0 < 1024) {
#pragma unroll
    for (int mi = 0; mi < 2; mi++)
#pragma unroll
      for (int ni = 0; ni < 4; ni++) {
        int rbase = row0 + mi * 16 + lg * 4;
        int col = col0 + ni * 16 + l15;
#pragma unroll
        for (int r = 0; r < 4; r++)
          Ckv[(long long)(rbase + r) * 1024 + col] = f2bf(acc[mi][ni][r]);
      }
  } else {
#pragma unroll
    for (int mi = 0; mi < 2; mi++)
#pragma unroll
      for (int ni = 0; ni < 4; ni++) {
        int nloc = wc * 64 + ni * 16 + l15;
#pragma unroll
        for (int r = 0; r < 4; r++) {
          int mloc = wr * 32 + mi * 16 + lg * 4 + r;
          Tt[nloc * 64 + (mloc ^ ((nloc & 7) << 3))] = f2bf(acc[mi][ni][r]);
        }
      }
    __syncthreads();
    const int nloc = t >> 1;
#pragma unroll
    for (int cc = 0; cc < 8; cc++) {
      int ci = (t & 1) * 8 + cc;
      uint2 v = *(const uint2*)(Tt + nloc * 64 +
                                (((ci >> 1) ^ (nloc & 7)) * 8 + (ci & 1) * 4));
      int nc = (ci >> 3) * 8 + 2 * (ci & 3) + ((ci >> 2) & 1);
      *(uint2*)(Cvt + (long long)(n0 - 1024 + nloc) * T_SEQ + m0 + nc * 4) = v;
    }
  }
}

// ---------------------------------------------------------------- RoPE (neox, fp64 angles); zeroes queue counters
__global__ void rope_all(unsigned short* __restrict__ qb,
                         unsigned short* __restrict__ kb,
                         const int* __restrict__ positions,
                         int* __restrict__ cnt) {
  if (blockIdx.x == 0 && threadIdx.x < 8) cnt[threadIdx.x] = 0;
  const int w = threadIdx.x >> 6, d = threadIdx.x & 63;
  const int gid = blockIdx.x * 4 + w;
  unsigned short* row;
  int t;
  bool isq;
  if (gid < T_SEQ * NQH) {
    int h = gid & (NQH - 1); t = gid >> 5;
    row = qb + (size_t)t * (NQH * HDIM) + (size_t)h * HDIM;
    isq = true;
  } else {
    int g = gid - T_SEQ * NQH;
    int h = g & (NKVH - 1); t = g >> 3;
    row = kb + (size_t)t * (NKVH * HDIM) + (size_t)h * HDIM;
    isq = false;
  }
  double inv = exp2(-(double)d * 0.20762050593046014);
  double ang = (double)positions[t] * inv;
  double c = cos(ang), s = sin(ang);
  if (isq) { c *= 0.12751744416986895; s *= 0.12751744416986895; }
  float x1 = bf2f(row[d]), x2 = bf2f(row[d + 64]);
  row[d]      = f2bf((float)((double)x1 * c - (double)x2 * s));
  row[d + 64] = f2bf((float)((double)x2 * c + (double)x1 * s));
}

// ---------------------------------------------------------------- flash attention v15: persistent queue + dbuf staging
__global__ __launch_bounds__(256) void attn_kernel(const unsigned short* __restrict__ qb,
                                                   const unsigned short* __restrict__ kb,
                                                   const unsigned short* __restrict__ vt,
                                                   unsigned short* __restrict__ ab,
                                                   int* __restrict__ cnt) {
  __shared__ unsigned short Ks[2][64 * 128];
  __shared__ unsigned short Vs[2][128 * 64];
  __shared__ int s_item;

  const int xcd = blockIdx.x & 7;
  const int kvh = xcd;
  const int t = threadIdx.x, lane = t & 63, w = t >> 6;
  const int l15 = lane & 15, lg = lane >> 4;

  auto stage = [&](int kts, int bsel) {
#pragma unroll
    for (int s = 0; s < 4; s++) {
      int c = t + s * 256;
      int row = c >> 4, chk = c & 15;
      GLOAD16(kb + (long long)(kts * 64 + row) * (NKVH * HDIM) + kvh * HDIM +
                  ((chk ^ (row & 7)) * 8),
              (char*)(&Ks[bsel][0]) + (w * 64 + s * 256) * 16);
    }
#pragma unroll
    for (int s = 0; s < 4; s++) {
      int c = t + s * 256;
      int row = c >> 3, chk = c & 7;
      GLOAD16(vt + (long long)(kvh * HDIM + row) * T_SEQ + kts * 64 +
                  ((chk ^ (row & 7)) * 8),
              (char*)(&Vs[bsel][0]) + (w * 64 + s * 256) * 16);
    }
  };

  for (;;) {
    __syncthreads();
    if (t == 0) s_item = atomicAdd(&cnt[xcd], 1);
    __syncthreads();
    const int item = s_item;
    if (item >= 128) break;
    const int j = 31 - (item >> 2);
    const int head = xcd * 4 + (item & 3);
    const int q0 = j * 64;

    bf16x8 qf[4];
#pragma unroll
    for (int kk = 0; kk < 4; kk++)
      qf[kk] = *(const bf16x8*)(qb + (long long)(q0 + w * 16 + l15) * (NQH * HDIM) +
                                head * HDIM + kk * 32 + lg * 8);

    f32x4 accO[8];
#pragma unroll
    for (int db = 0; db < 8; db++) accO[db] = (f32x4){0.f, 0.f, 0.f, 0.f};
    float mrun = -3e38f, lrun = 0.f;

    stage(0, 0);
    for (int kt = 0; kt <= j; kt++) {
      const int cur = kt & 1;
      __syncthreads();
      if (kt < j) stage(kt + 1, cur ^ 1);

      f32x4 accS[4];
#pragma unroll
      for (int kc = 0; kc < 4; kc++) accS[kc] = (f32x4){0.f, 0.f, 0.f, 0.f};
      __builtin_amdgcn_s_setprio(1);
#pragma unroll
      for (int kk = 0; kk < 4; kk++)
#pragma unroll
        for (int kc = 0; kc < 4; kc++) {
          int row = kc * 16 + l15;
          bf16x8 a = *(const bf16x8*)(&Ks[cur][0] + row * 128 + (((kk * 4 + lg) ^ (l15 & 7)) * 8));
          accS[kc] = mfma_bf16(a, qf[kk], accS[kc]);
        }
      __builtin_amdgcn_s_setprio(0);

      float pm[4][4];
      if (kt == j) {
        const int qloc = w * 16 + l15;
#pragma unroll
        for (int kc = 0; kc < 4; kc++)
#pragma unroll
          for (int r = 0; r < 4; r++)
            pm[kc][r] = (kc * 16 + lg * 4 + r > qloc) ? -3e38f : accS[kc][r];
      } else {
#pragma unroll
        for (int kc = 0; kc < 4; kc++)
#pragma unroll
          for (int r = 0; r < 4; r++) pm[kc][r] = accS[kc][r];
      }

      float rm = pm[0][0];
#pragma unroll
      for (int kc = 0; kc < 4; kc++)
#pragma unroll
        for (int r = 0; r < 4; r++) rm = fmaxf(rm, pm[kc][r]);
      if (__any(rm > mrun + 8.f)) {
        rm = fmaxf(rm, __shfl_xor(rm, 16, 64));
        rm = fmaxf(rm, __shfl_xor(rm, 32, 64));
        float mn = fmaxf(mrun, rm);
        float corr = exp2f(mrun - mn);
        mrun = mn;
        lrun *= corr;
        float cO[4];
#pragma unroll
        for (int r = 0; r < 4; r++) cO[r] = __shfl(corr, lg * 4 + r, 64);
#pragma unroll
        for (int db = 0; db < 8; db++)
#pragma unroll
          for (int r = 0; r < 4; r++) accO[db][r] *= cO[r];
      }

      float p[4][4];
#pragma unroll
      for (int kc = 0; kc < 4; kc++)
#pragma unroll
        for (int r = 0; r < 4; r++) {
          p[kc][r] = exp2f(pm[kc][r] - mrun);
          lrun += p[kc][r];
        }
      bf16x8 pa0, pa1;
#pragma unroll
      for (int jj = 0; jj < 8; jj++) {
        pa0[jj] = (__bf16)p[(jj >> 2)][jj & 3];
        pa1[jj] = (__bf16)p[2 + (jj >> 2)][jj & 3];
      }

      __builtin_amdgcn_s_setprio(1);
#pragma unroll
      for (int db = 0; db < 8; db++) {
        int vrow = db * 16 + l15;
        bf16x8 b = *(const bf16x8*)(&Vs[cur][0] + vrow * 64 + ((lg ^ (vrow & 7)) * 8));
        accO[db] = mfma_bf16(pa0, b, accO[db]);
      }
#pragma unroll
      for (int db = 0; db < 8; db++) {
        int vrow = db * 16 + l15;
        bf16x8 b = *(const bf16x8*)(&Vs[cur][0] + vrow * 64 + (((4 + lg) ^ (vrow & 7)) * 8));
        accO[db] = mfma_bf16(pa1, b, accO[db]);
      }
      __builtin_amdgcn_s_setprio(0);
    }

    lrun += __shfl_xor(lrun, 16, 64);
    lrun += __shfl_xor(lrun, 32, 64);
    float lO[4];
#pragma unroll
    for (int r = 0; r < 4; r++) lO[r] = __shfl(lrun, lg * 4 + r, 64);
#pragma unroll
    for (int db = 0; db < 8; db++)
#pragma unroll
      for (int r = 0; r < 4; r++) {
        int qr = q0 + w * 16 + lg * 4 + r;
        int col = head * HDIM + db * 16 + l15;
        ((__bf16*)ab)[(long long)qr * (NQH * HDIM) + col] = (__bf16)(accO[db][r] / lO[r]);
      }
  }
}

// ---------------------------------------------------------------- launch
extern "C" void kernel_launch(void* const* d_in, const int* in_sizes, int n_in,
                              void* d_out, int out_size, void* d_ws, size_t ws_size,
                              hipStream_t stream) {
  const int*   positions = (const int*)d_in[0];
  const float* hs = (const float*)d_in[1];
  const float* wq = (const float*)d_in[2];
  const float* wk = (const float*)d_in[3];
  const float* wv = (const float*)d_in[4];
  const float* wo = (const float*)d_in[5];
  float* out = (float*)d_out;

  // workspace: wqt 33.6 + wkvt 16.8 + hb/ab 16.8 + qb 16.8 + kb 4.2 + vtb 4.2 + cnt = 92.3 MB (proven)
  const size_t SZ_WQT = (size_t)HID * HID * 2;
  const size_t SZ_WKV = (size_t)2048 * HID * 2;
  const size_t SZ_HB  = (size_t)T_SEQ * HID * 2;
  const size_t SZ_QB  = (size_t)T_SEQ * NQH * HDIM * 2;
  const size_t SZ_KB  = (size_t)T_SEQ * NKVH * HDIM * 2;
  const size_t need = SZ_WQT + SZ_WKV + SZ_HB + SZ_QB + SZ_KB * 2 + 64;
  if (ws_size < need) return;  // absmax 4.625 signature

  char* p = (char*)d_ws;
  unsigned short* wqt  = (unsigned short*)p; p += SZ_WQT;  // reused for wo_t at the end
  unsigned short* wkvt = (unsigned short*)p; p += SZ_WKV;
  unsigned short* hb   = (unsigned short*)p; p += SZ_HB;
  unsigned short* qb   = (unsigned short*)p; p += SZ_QB;
  unsigned short* kb   = (unsigned short*)p; p += SZ_KB;
  unsigned short* vtb  = (unsigned short*)p; p += SZ_KB;
  int* cnt = (int*)p;
  unsigned short* ab   = hb;  // alias: hb dead after KV-GEMM

  prep_all<<<14336, 256, 0, stream>>>(hs, hb, wq, wqt, wk, wv, wkvt);

  gemm_bt<0><<<dim3((NQH * HDIM) / 128, T_SEQ / 128), 256, 0, stream>>>(hb, wqt, qb, T_SEQ, NQH * HDIM, HID);
  gemm_kv64<<<dim3(16, 32), 256, 0, stream>>>(hb, wkvt, kb, vtb);

  rope_all<<<(T_SEQ * (NQH + NKVH)) / 4, 256, 0, stream>>>(qb, kb, positions, cnt);

  attn_kernel<<<512, 256, 0, stream>>>(qb, kb, vtb, ab, cnt);

  transpose_conv<<<dim3(HID / 64, (NQH * HDIM) / 64), 256, 0, stream>>>(wo, wqt, NQH * HDIM, HID);
  gemm_bt<2><<<dim3(HID / 128, T_SEQ / 128), 256, 0, stream>>>(ab, wqt, out, T_SEQ, HID, NQH * HDIM);
}